// Round 1
// baseline (626.134 us; speedup 1.0000x reference)
//
#include <hip/hip_runtime.h>

// out[b, n] = sum_k w[b,k] * archs[k,n] * (n % 257 != 0)   for n in [0, 65536)
// M=2048, K=32, N=65536. Write-bound: 512 MiB output -> ~85 us floor at 6.3 TB/s.
//
// Tiling: each block owns N_CHUNK=1024 contiguous positions (256 thr x float4)
// and a B_CHUNK=128 batch slice. archs slice lives in registers (32 x 4 floats
// per thread), reused across 128 batches.
//
// R1 changes vs baseline (614 us, kernel ~275 us inferred):
//  - plain dwordx4 stores (NT stores suspected of capping write BW at ~2 TB/s;
//    the harness fill proves the plain-store path sustains 6.3 TB/s)
//  - 1-deep prefetch of next b's 32 weights (decouple s_load latency from FMAs)
//  - __launch_bounds__(256,3): pin VGPR <= ~170 so >=3 waves/SIMD resident

typedef float vfloat4 __attribute__((ext_vector_type(4)));

constexpr int K = 32;
constexpr int D = 256;
constexpr int N = D * D;        // 65536
constexpr int NPT = 4;          // positions per thread (one float4)
constexpr int THREADS = 256;
constexpr int N_CHUNK = THREADS * NPT;  // 1024
constexpr int B_CHUNK = 128;

__global__ __launch_bounds__(THREADS, 3)
void explainer_kernel(const float* __restrict__ w,
                      const float* __restrict__ archs,
                      float* __restrict__ out,
                      int B) {
    const int nbase = blockIdx.x * N_CHUNK + threadIdx.x * NPT;
    const int bbase = blockIdx.y * B_CHUNK;

    // Load archs slice into registers: a[k][j] = archs[k, nbase+j], diag zeroed.
    float a[K][NPT];
#pragma unroll
    for (int k = 0; k < K; ++k) {
        const vfloat4 v = *reinterpret_cast<const vfloat4*>(archs + (size_t)k * N + nbase);
        a[k][0] = v.x; a[k][1] = v.y; a[k][2] = v.z; a[k][3] = v.w;
    }
    // Diagonal mask: n = d*256 + e has d==e iff n % 257 == 0.
#pragma unroll
    for (int j = 0; j < NPT; ++j) {
        if (((nbase + j) % 257) == 0) {
#pragma unroll
            for (int k = 0; k < K; ++k) a[k][j] = 0.0f;
        }
    }

    const int bend = min(bbase + B_CHUNK, B);

    // Weights viewed as 8 x float4 per batch row; b is block-uniform -> s_load.
    const vfloat4* __restrict__ wv = reinterpret_cast<const vfloat4*>(w);

    // Prime the pipeline with row bbase.
    vfloat4 wcur[K / 4];
#pragma unroll
    for (int q = 0; q < K / 4; ++q) wcur[q] = wv[(size_t)bbase * (K / 4) + q];

    float* __restrict__ optr = out + (size_t)bbase * N + nbase;

    for (int b = bbase; b < bend; ++b) {
        // Prefetch next row's weights; the s_waitcnt for these lands AFTER the
        // current FMA block, hiding the ~260cy scalar-load latency.
        const int bn = (b + 1 < bend) ? (b + 1) : b;
        vfloat4 wnext[K / 4];
#pragma unroll
        for (int q = 0; q < K / 4; ++q) wnext[q] = wv[(size_t)bn * (K / 4) + q];

        float acc0 = 0.f, acc1 = 0.f, acc2 = 0.f, acc3 = 0.f;
#pragma unroll
        for (int q = 0; q < K / 4; ++q) {
            const vfloat4 wq = wcur[q];
            acc0 = fmaf(wq.x, a[4 * q + 0][0], acc0);
            acc1 = fmaf(wq.x, a[4 * q + 0][1], acc1);
            acc2 = fmaf(wq.x, a[4 * q + 0][2], acc2);
            acc3 = fmaf(wq.x, a[4 * q + 0][3], acc3);
            acc0 = fmaf(wq.y, a[4 * q + 1][0], acc0);
            acc1 = fmaf(wq.y, a[4 * q + 1][1], acc1);
            acc2 = fmaf(wq.y, a[4 * q + 1][2], acc2);
            acc3 = fmaf(wq.y, a[4 * q + 1][3], acc3);
            acc0 = fmaf(wq.z, a[4 * q + 2][0], acc0);
            acc1 = fmaf(wq.z, a[4 * q + 2][1], acc1);
            acc2 = fmaf(wq.z, a[4 * q + 2][2], acc2);
            acc3 = fmaf(wq.z, a[4 * q + 2][3], acc3);
            acc0 = fmaf(wq.w, a[4 * q + 3][0], acc0);
            acc1 = fmaf(wq.w, a[4 * q + 3][1], acc1);
            acc2 = fmaf(wq.w, a[4 * q + 3][2], acc2);
            acc3 = fmaf(wq.w, a[4 * q + 3][3], acc3);
        }

        vfloat4 o;
        o.x = acc0; o.y = acc1; o.z = acc2; o.w = acc3;
        *reinterpret_cast<vfloat4*>(optr) = o;   // plain store (was nontemporal)
        optr += N;

#pragma unroll
        for (int q = 0; q < K / 4; ++q) wcur[q] = wnext[q];
    }
}

extern "C" void kernel_launch(void* const* d_in, const int* in_sizes, int n_in,
                              void* d_out, int out_size, void* d_ws, size_t ws_size,
                              hipStream_t stream) {
    const float* w     = (const float*)d_in[0];   // (B, 32)
    const float* archs = (const float*)d_in[1];   // (32, 256, 256)
    float* out = (float*)d_out;                   // (B, 256, 256)

    const int B = in_sizes[0] / K;                // 2048
    const int grid_x = N / N_CHUNK;               // 64
    const int grid_y = (B + B_CHUNK - 1) / B_CHUNK;  // 16

    dim3 grid(grid_x, grid_y);
    dim3 block(THREADS);
    explainer_kernel<<<grid, block, 0, stream>>>(w, archs, out, B);
}

// Round 2
// 600.106 us; speedup vs baseline: 1.0434x; 1.0434x over previous
//
#include <hip/hip_runtime.h>

// out[b, n] = sum_k w[b,k] * archs[k,n] * (n % 257 != 0)   for n in [0, 65536)
// M=2048, K=32, N=65536. Write-bound: 512 MiB output -> ~85 us floor at 6.3 TB/s.
//
// R2 theory: kernel is latency/occupancy-bound (1.9 TB/s write, 20% of VALU
// issue ceiling, 31% of store ceiling -> nothing saturated). Fix:
//  - NPT=2: archs slice a[32][2] = 64 VGPR (was 128) -> ~80 VGPR total
//    -> 6 waves/SIMD instead of 3 (2x latency hiding)
//  - B_CHUNK=64: 4096 blocks (was 1024) -> 16 blocks/CU, no residency tail
//  - keep 1-deep scalar weight prefetch + plain dwordx2 stores

typedef float vfloat2 __attribute__((ext_vector_type(2)));
typedef float vfloat4 __attribute__((ext_vector_type(4)));

constexpr int K = 32;
constexpr int D = 256;
constexpr int N = D * D;        // 65536
constexpr int NPT = 2;          // positions per thread (one float2)
constexpr int THREADS = 256;
constexpr int N_CHUNK = THREADS * NPT;  // 512
constexpr int B_CHUNK = 64;

__global__ __launch_bounds__(THREADS, 5)
void explainer_kernel(const float* __restrict__ w,
                      const float* __restrict__ archs,
                      float* __restrict__ out,
                      int B) {
    const int nbase = blockIdx.x * N_CHUNK + threadIdx.x * NPT;
    const int bbase = blockIdx.y * B_CHUNK;

    // archs slice in registers: a0[k] = archs[k, nbase], a1[k] = archs[k, nbase+1]
    float a0[K], a1[K];
#pragma unroll
    for (int k = 0; k < K; ++k) {
        const vfloat2 v = *reinterpret_cast<const vfloat2*>(archs + (size_t)k * N + nbase);
        a0[k] = v.x; a1[k] = v.y;
    }
    // Diagonal mask: n = d*256 + e has d==e iff n % 257 == 0.
    if ((nbase % 257) == 0) {
#pragma unroll
        for (int k = 0; k < K; ++k) a0[k] = 0.0f;
    }
    if (((nbase + 1) % 257) == 0) {
#pragma unroll
        for (int k = 0; k < K; ++k) a1[k] = 0.0f;
    }

    const int bend = min(bbase + B_CHUNK, B);

    // Weights: block-uniform rows -> scalar loads, 1-deep prefetch.
    const vfloat4* __restrict__ wv = reinterpret_cast<const vfloat4*>(w);

    vfloat4 wcur[K / 4];
#pragma unroll
    for (int q = 0; q < K / 4; ++q) wcur[q] = wv[(size_t)bbase * (K / 4) + q];

    float* __restrict__ optr = out + (size_t)bbase * N + nbase;

    for (int b = bbase; b < bend; ++b) {
        const int bn = (b + 1 < bend) ? (b + 1) : b;
        vfloat4 wnext[K / 4];
#pragma unroll
        for (int q = 0; q < K / 4; ++q) wnext[q] = wv[(size_t)bn * (K / 4) + q];

        float acc0 = 0.f, acc1 = 0.f;
#pragma unroll
        for (int q = 0; q < K / 4; ++q) {
            const vfloat4 wq = wcur[q];
            acc0 = fmaf(wq.x, a0[4 * q + 0], acc0);
            acc1 = fmaf(wq.x, a1[4 * q + 0], acc1);
            acc0 = fmaf(wq.y, a0[4 * q + 1], acc0);
            acc1 = fmaf(wq.y, a1[4 * q + 1], acc1);
            acc0 = fmaf(wq.z, a0[4 * q + 2], acc0);
            acc1 = fmaf(wq.z, a1[4 * q + 2], acc1);
            acc0 = fmaf(wq.w, a0[4 * q + 3], acc0);
            acc1 = fmaf(wq.w, a1[4 * q + 3], acc1);
        }

        vfloat2 o; o.x = acc0; o.y = acc1;
        *reinterpret_cast<vfloat2*>(optr) = o;
        optr += N;

#pragma unroll
        for (int q = 0; q < K / 4; ++q) wcur[q] = wnext[q];
    }
}

extern "C" void kernel_launch(void* const* d_in, const int* in_sizes, int n_in,
                              void* d_out, int out_size, void* d_ws, size_t ws_size,
                              hipStream_t stream) {
    const float* w     = (const float*)d_in[0];   // (B, 32)
    const float* archs = (const float*)d_in[1];   // (32, 256, 256)
    float* out = (float*)d_out;                   // (B, 256, 256)

    const int B = in_sizes[0] / K;                // 2048
    const int grid_x = N / N_CHUNK;               // 128
    const int grid_y = (B + B_CHUNK - 1) / B_CHUNK;  // 32

    dim3 grid(grid_x, grid_y);
    dim3 block(THREADS);
    explainer_kernel<<<grid, block, 0, stream>>>(w, archs, out, B);
}